// Round 1
// baseline (817.744 us; speedup 1.0000x reference)
//
#include <hip/hip_runtime.h>
#include <math.h>
#include <string.h>

// V2VNetFusion on MI355X, round 5: T14 software pipeline on the conv.
// Round-4 structure (f16 MFMA implicit-GEMM, pixel-interleaved f16
// [half][pix][32ch], XOR-swizzled LDS input tile) was stall-bound:
// MfmaUtil 21% ~= the un-pipelined 2-barrier-per-K-step ceiling; the
// global->LDS stage latency was fully exposed between barriers.
// Changes:
//  1. Register staging (issue-early/write-late): kb+1's input+weight
//     global loads are issued at the start of kb's compute phase
//     (vmcnt domain) and ds_written at the top of kb+1. MFMA operands
//     are ds_reads (lgkm domain) -> in-flight loads never drained
//     during compute.
//  2. t=0 GATES launches only the update half (z=2, grp_base=2):
//     h=0 makes reset*h == 0 and CAND at t=0 (nkb=4) never reads rhb.
#define HH 200
#define WW 352
#define HWSZ (HH*WW)          // 70400
#define CHW (64L*HWSZ)        // one (64,H,W) tensor, elems

enum { EPI_MSG=0, EPI_GATES=1, EPI_CAND=2 };

typedef __attribute__((ext_vector_type(8))) _Float16 f16x8;
typedef __attribute__((ext_vector_type(4))) float f32x4;
typedef __attribute__((ext_vector_type(4))) unsigned int uint4v;
typedef __attribute__((ext_vector_type(4))) unsigned short ushort4v;

__device__ __forceinline__ unsigned short f2h(float f) {
    _Float16 h = (_Float16)f;                    // v_cvt_f16_f32 (RTE)
    return __builtin_bit_cast(unsigned short, h);
}
__device__ __forceinline__ float h2f(unsigned short u) {
    return (float)__builtin_bit_cast(_Float16, u);
}

// Prepack conv weights to f16, LDS-ready lane-major layout:
// [cogrp][kb][sh(9)][cf(2)][lane(64)][8ch]; 9216 f16 per (cogrp,kb) chunk.
// lane = q*16+n16 -> co = cf*16+n16, ch = q*8+j.   msg: 2x4, gates: 4x6, cand: 2x6
__global__ void prepack_k(const float* __restrict__ mw,
                          const float* __restrict__ gw,
                          const float* __restrict__ cw,
                          unsigned short* __restrict__ pw)
{
    const int MSG_I = 2*4*9216;
    const int GAT_I = 4*6*9216;
    const int CAN_I = 2*6*9216;
    int idx = blockIdx.x*256 + threadIdx.x;
    const float* w; int cin, nkb, rel; unsigned short* base;
    if (idx < MSG_I)              { w=mw; cin=128; nkb=4; rel=idx;              base=pw; }
    else if (idx < MSG_I+GAT_I)   { w=gw; cin=192; nkb=6; rel=idx-MSG_I;        base=pw+73728; }
    else if (idx < MSG_I+GAT_I+CAN_I) { w=cw; cin=192; nkb=6; rel=idx-MSG_I-GAT_I; base=pw+294912; }
    else return;
    int chunk = rel / 9216, r = rel - chunk*9216;
    int j = r & 7, lane = (r >> 3) & 63, cfsh = r >> 9;
    int cf = cfsh & 1, sh = cfsh >> 1;
    int q = lane >> 4, n16 = lane & 15;
    int co = cf*16 + n16, ch = q*8 + j;
    int cogrp = chunk / nkb, kb = chunk - cogrp*nkb;
    float f = w[(((long)(cogrp*32+co))*cin + kb*32+ch)*9 + sh];
    base[(size_t)chunk*9216 + r] = f2h(f);
}

// Convert x (2 agents x 4 t) fp32 planar -> f16 interleaved [t][half][pix][32].
// xb1 goes into d_out[0..1] region (dead until step 0 writes out[0]).
__global__ void convert_all_k(const float* __restrict__ x,
                              unsigned short* __restrict__ xb0_all,
                              unsigned short* __restrict__ xb1_all)
{
    int idx = blockIdx.x*256 + threadIdx.x;      // 4,505,600 total
    int cp   = idx & 15;
    int rest = idx >> 4;
    int px4  = rest % 17600;
    int r2   = rest / 17600;                      // 0..15
    int hb = r2 & 1, ag = (r2 >> 1) & 1, t = r2 >> 2;
    const float* src = x + ((size_t)(ag*4 + t))*CHW
                         + (size_t)(hb*32 + 2*cp)*HWSZ + (size_t)px4*4;
    float4 a = *(const float4*)src;
    float4 b = *(const float4*)(src + HWSZ);
    unsigned int* dst = (unsigned int*)((ag ? xb1_all : xb0_all)
                        + (size_t)t*CHW + (size_t)hb*HWSZ*32) + (size_t)px4*64 + cp;
    dst[0]  = (unsigned)f2h(a.x) | ((unsigned)f2h(b.x) << 16);
    dst[16] = (unsigned)f2h(a.y) | ((unsigned)f2h(b.y) << 16);
    dst[32] = (unsigned)f2h(a.z) | ((unsigned)f2h(b.z) << 16);
    dst[48] = (unsigned)f2h(a.w) | ((unsigned)f2h(b.w) << 16);
}

// Block: 32 out-ch x (16 rows x 32 cols), 512 thr = 8 waves; wave w = rows
// 2w,2w+1. LDS: input [18][34][32] f16 XOR-swizzled (39168 B) + weights
// [9][2][64][8] (18432 B) = 57.6 KB -> 2 blocks/CU.
// K-loop pipeline per kb:
//   barrier -> ds_write staged regs (waits vmcnt(0); loads had the whole
//   previous compute phase in flight) -> barrier -> issue kb+1 global
//   loads -> 9-shift MFMA phase (pure lgkm-domain ds_reads).
template<int EPI>
__global__ __launch_bounds__(512, 4)
void conv_mfma_k(const unsigned short* __restrict__ seg0b,
                 const unsigned short* __restrict__ seg1b,
                 const unsigned short* __restrict__ seg2b,
                 int nkb, int nkb_stride, int grp_base,
                 const unsigned short* __restrict__ pw,
                 const float* __restrict__ bias,
                 const unsigned short* e_hb,     // f16 interl. h_{t-1} (null @t=0)
                 const unsigned short* __restrict__ e_updb, // CAND: upd f16 interl.
                 float* out_f,                   // CAND: out[t] fp32 planar
                 unsigned short* out_b,          // MSG: aggb(t<3) GATES: rhb CAND: hb
                 unsigned short* out_b2)         // MSG: aggb3    GATES: updb
{
    __shared__ unsigned short s_in[612*32];    // [pos=row*34+col][32ch] 39168 B
    __shared__ unsigned short s_w[9*2*64*8];   // [sh][cf][lane][8]     18432 B

    const int tid  = threadIdx.x;
    const int lane = tid & 63;
    const int wv   = tid >> 6;
    const int n16  = lane & 15;
    const int q    = lane >> 4;
    const int q8   = q * 8;
    (void)q8;

    const int z = blockIdx.z;
    int grp, ts = 0;
    if (EPI == EPI_MSG) { ts = z >> 1; grp = z & 1; } else grp = z + grp_base;

    const unsigned short* s0 = seg0b + (EPI==EPI_MSG ? (size_t)ts*CHW : 0);
    const unsigned short* s1 = seg1b + (EPI==EPI_MSG ? (size_t)ts*CHW : 0);
    unsigned short* ob = out_b;
    if (EPI == EPI_MSG) ob = (ts < 3) ? out_b + (size_t)ts*CHW : out_b2;

    const int x0p = blockIdx.x * 32;
    const int y0  = blockIdx.y * 16;

    // ---- kb-invariant staging descriptors (input tile: 2448 16B granules)
    int poff[5], slot[5];
#pragma unroll
    for (int k = 0; k < 5; ++k) {
        const int i = tid + 512*k;
        slot[k] = -1; poff[k] = -1;
        if (i < 2448) {
            const int pos = i >> 2;
            const int g   = i & 3;
            const int row = pos / 34;
            const int col = pos - row*34;
            const int gy = y0 + row - 1;
            const int gx = x0p + col - 1;
            const int sw = (g ^ pos ^ (pos >> 2)) & 3;
            slot[k] = (pos << 5) + (sw << 3);
            if ((unsigned)gy < (unsigned)HH && (unsigned)gx < (unsigned)WW)
                poff[k] = ((gy*WW + gx) << 5) + (g << 3);
        }
    }

    uint4v st[5];      // staged input granules for next kb
    uint4v wst[3];     // staged weight granules (1152 per kb)

    auto srcof = [&](int kb) -> const unsigned short* {
        return ((kb < 2) ? s0 : (kb < 4) ? s1 : seg2b) + (size_t)(kb & 1)*HWSZ*32;
    };
    auto issue_in = [&](const unsigned short* src) {
#pragma unroll
        for (int k = 0; k < 5; ++k) {
            uint4v v = (uint4v){0u,0u,0u,0u};
            if (poff[k] >= 0) v = *(const uint4v*)(src + poff[k]);
            st[k] = v;
        }
    };
    auto issue_w = [&](int kb) {
        const uint4v* wsrc = (const uint4v*)(pw + (size_t)(grp*nkb_stride + kb)*9216);
#pragma unroll
        for (int k = 0; k < 3; ++k) {
            const int j = tid + 512*k;
            if (j < 1152) wst[k] = wsrc[j];
        }
    };

    f32x4 acc[2][4];
#pragma unroll
    for (int cf=0; cf<2; ++cf)
#pragma unroll
        for (int p=0; p<4; ++p) acc[cf][p] = (f32x4){0.f,0.f,0.f,0.f};

    // prologue: stage kb=0
    issue_in(srcof(0));
    issue_w(0);

    for (int kb = 0; kb < nkb; ++kb) {
        __syncthreads();                 // all waves done reading s_in/s_w
        // ---- write-late: staged regs -> LDS (vmcnt(0) lands here, covered
        //      by the previous kb's compute phase)
#pragma unroll
        for (int k = 0; k < 5; ++k)
            if (slot[k] >= 0) *(uint4v*)&s_in[slot[k]] = st[k];
#pragma unroll
        for (int k = 0; k < 3; ++k) {
            const int j = tid + 512*k;
            if (j < 1152) ((uint4v*)s_w)[j] = wst[k];
        }
        __syncthreads();                 // tile ready
        // ---- issue-early: next kb's global loads fly during this compute
        if (kb + 1 < nkb) {
            issue_in(srcof(kb + 1));
            issue_w(kb + 1);
        }
        // ---- 9 shifts x 4 px-frags x 2 co-frags (single f16 MFMA each)
#pragma unroll
        for (int ky = 0; ky < 3; ++ky) {
#pragma unroll
            for (int kx = 0; kx < 3; ++kx) {
                const int sh = ky*3 + kx;
                f16x8 aw0 = *(const f16x8*)&s_w[((sh*2 + 0)*64 + lane)*8];
                f16x8 aw1 = *(const f16x8*)&s_w[((sh*2 + 1)*64 + lane)*8];
#pragma unroll
                for (int p = 0; p < 4; ++p) {
                    const int rl = 2*wv + (p >> 1) + ky;
                    const int cl = 16*(p & 1) + n16 + kx;
                    const int pos = rl*34 + cl;
                    const int sw = (q ^ pos ^ (pos >> 2)) & 3;
                    f16x8 bfr = *(const f16x8*)&s_in[(pos << 5) + (sw << 3)];
                    acc[0][p] = __builtin_amdgcn_mfma_f32_16x16x32_f16(aw0, bfr, acc[0][p], 0, 0, 0);
                    acc[1][p] = __builtin_amdgcn_mfma_f32_16x16x32_f16(aw1, bfr, acc[1][p], 0, 0, 0);
                }
            }
        }
    }

    // ---- epilogue. C/D: pixel = lane&15, co = (lane>>4)*4 + reg
#pragma unroll
    for (int cf = 0; cf < 2; ++cf) {
        const int cobase = grp*32 + cf*16 + q*4;   // global co of reg 0
        const int cmod   = cf*16 + q*4;            // co within 32-plane
#pragma unroll
        for (int p = 0; p < 4; ++p) {
            const int row = y0 + 2*wv + (p >> 1);
            const int col = x0p + 16*(p & 1) + n16;
            if (row >= HH) continue;
            const long pix = (long)row*WW + col;
            const size_t iidx = (((size_t)(grp & 1)*HWSZ + pix) << 5) + cmod;
            float v[4];
#pragma unroll
            for (int r = 0; r < 4; ++r) v[r] = acc[cf][p][r] + bias[cobase + r];

            if (EPI == EPI_MSG) {
                ushort4v xv = *(const ushort4v*)&s0[iidx];
                ushort4v s;
#pragma unroll
                for (int r = 0; r < 4; ++r)
                    s[r] = f2h(0.5f*(h2f(xv[r]) + v[r]));
                *(ushort4v*)&ob[iidx] = s;
            } else if (EPI == EPI_GATES) {
                if (grp < 2) {   // reset -> rh = sigmoid * h (f16 interleaved)
                    const size_t ridx = (((size_t)grp*HWSZ + pix) << 5) + cmod;
                    ushort4v hv = e_hb ? *(const ushort4v*)&e_hb[ridx]
                                       : (ushort4v){0,0,0,0};
                    ushort4v s;
#pragma unroll
                    for (int r = 0; r < 4; ++r) {
                        float g = 1.f/(1.f + __expf(-v[r]));
                        s[r] = f2h(g * h2f(hv[r]));
                    }
                    *(ushort4v*)&out_b[ridx] = s;
                } else {         // update -> updb (f16 interleaved)
                    const size_t uidx = ((((size_t)(grp-2))*HWSZ + pix) << 5) + cmod;
                    ushort4v s;
#pragma unroll
                    for (int r = 0; r < 4; ++r)
                        s[r] = f2h(1.f/(1.f + __expf(-v[r])));
                    *(ushort4v*)&out_b2[uidx] = s;
                }
            } else {             // CAND: h_next -> out fp32 planar + hb f16
                ushort4v uv = *(const ushort4v*)&e_updb[iidx];
                ushort4v hv = e_hb ? *(const ushort4v*)&e_hb[iidx]
                                   : (ushort4v){0,0,0,0};
                ushort4v s;
#pragma unroll
                for (int r = 0; r < 4; ++r) {
                    float cnm = tanhf(v[r]);
                    float u   = h2f(uv[r]);
                    float hn  = (1.f - u)*h2f(hv[r]) + u*cnm;
                    out_f[(long)(cobase+r)*HWSZ + pix] = hn;
                    s[r] = f2h(hn);
                }
                *(ushort4v*)&out_b[iidx] = s;
            }
        }
    }
}

// ws (u16 units): xb0_all 4C | aggb3 C | rhb C | updb C | hb C | pw 405504
//   = 72.9 MB.   d_out aliases: xb1_all = out[0..1] (dead until step 0),
//   aggb[0..2] = out[2..3] (aggb[t] dead before its region is written).
extern "C" void kernel_launch(void* const* d_in, const int* in_sizes, int n_in,
                              void* d_out, int out_size, void* d_ws, size_t ws_size,
                              hipStream_t stream)
{
    const float* x       = (const float*)d_in[0];
    const float* msg_w   = (const float*)d_in[1];
    const float* msg_b   = (const float*)d_in[2];
    const float* gates_w = (const float*)d_in[3];
    const float* gates_b = (const float*)d_in[4];
    const float* can_w   = (const float*)d_in[5];
    const float* can_b   = (const float*)d_in[6];
    float* out = (float*)d_out;

    unsigned short* W       = (unsigned short*)d_ws;
    unsigned short* xb0_all = W;                  // [4][2][HWSZ][32]
    unsigned short* aggb3   = W + 4*CHW;
    unsigned short* rhb     = W + 5*CHW;
    unsigned short* updb    = W + 6*CHW;
    unsigned short* hb      = W + 7*CHW;
    unsigned short* pw      = W + 8*CHW;          // 405504 u16
    unsigned short* pw_msg  = pw;
    unsigned short* pw_gat  = pw + 73728;
    unsigned short* pw_can  = pw + 294912;

    unsigned short* outU16   = (unsigned short*)d_out;
    unsigned short* xb1_all  = outU16;            // 4*CHW u16 = out[0..1]
    unsigned short* aggbase  = outU16 + 4*CHW;    // aggb[0..2] = out[2..3]

    prepack_k<<<dim3(1584), dim3(256), 0, stream>>>(msg_w, gates_w, can_w, pw);
    convert_all_k<<<dim3(17600), dim3(256), 0, stream>>>(x, xb0_all, xb1_all);

    // msg for all 4 t in one dispatch: Cin=[x0|x1], Cout=64 -> aggb[t]
    conv_mfma_k<EPI_MSG><<<dim3(11,13,8), dim3(512), 0, stream>>>(
        xb0_all, xb1_all, nullptr, 4, 4, 0, pw_msg, msg_b,
        nullptr, nullptr, nullptr, aggbase, aggb3);

    for (int t = 0; t < 4; ++t) {
        const unsigned short* xt  = xb0_all + (size_t)t*CHW;
        const unsigned short* agt = (t < 3) ? aggbase + (size_t)t*CHW : aggb3;
        const unsigned short* hprev = t ? hb : nullptr;

        // gates: Cin=[x|agg|h], Cout=128 -> rhb, updb.
        // t=0: h==0 -> reset*h==0 and CAND(nkb=4) never reads rhb, so
        // launch only the update half (z=2, grp_base=2).
        conv_mfma_k<EPI_GATES><<<dim3(11,13, t ? 4 : 2), dim3(512), 0, stream>>>(
            xt, agt, hb, t ? 6 : 4, 6, t ? 0 : 2, pw_gat, gates_b,
            hprev, nullptr, nullptr, rhb, updb);
        // cand: Cin=[x|agg|rh], Cout=64 -> out[t] fp32 + hb f16
        conv_mfma_k<EPI_CAND><<<dim3(11,13,2), dim3(512), 0, stream>>>(
            xt, agt, rhb, t ? 6 : 4, 6, 0, pw_can, can_b,
            hprev, updb, out + (size_t)t*CHW, hb, nullptr);
    }
}

// Round 3
// 463.175 us; speedup vs baseline: 1.7655x; 1.7655x over previous
//
#include <hip/hip_runtime.h>
#include <math.h>
#include <string.h>

// V2VNetFusion on MI355X, round 7: cf=4 (co=64/block) + safe T3 2-phase.
// Round-5: reg-staged pipeline spilled (scratch traffic). Round-6: raw
// s_barrier pipeline -> container unresponsive (hang-risk class).
// This round:
//  1. LDS-read pressure was the compute-phase bottleneck (8 waves x 54
//     b128 x ~12cy ~= 5.2K cyc/CU/kb vs 0.7K MFMA). co=64 per block
//     (cf=4) halves LDS-read cycles per FLOP (reads:MFMA 0.75 -> 0.5).
//  2. Pipeline via plain __syncthreads(): stage(kb+1) DMAs issued AFTER
//     the barrier, compute(kb) runs immediately; the next barrier's
//     implicit vmcnt(0) drains DMAs that had a full compute phase in
//     flight. Same overlap as raw-barrier version, standard semantics.
//  3. Staging via global_load_lds (zero staging VGPRs; rule #21: linear
//     LDS dest + inverse-XOR-swizzled per-lane SOURCE). 400-granule halo
//     reg-staged (1 uint4v/thread, pre-zeroed slots).
//  4. t=0 GATES: update half only (h=0 => reset*h==0, rhb unread).
#define HH 200
#define WW 352
#define HWSZ (HH*WW)          // 70400
#define CHW (64L*HWSZ)        // one (64,H,W) tensor, elems

enum { EPI_MSG=0, EPI_GATES=1, EPI_CAND=2 };

typedef __attribute__((ext_vector_type(8))) _Float16 f16x8;
typedef __attribute__((ext_vector_type(4))) float f32x4;
typedef __attribute__((ext_vector_type(4))) unsigned int uint4v;
typedef __attribute__((ext_vector_type(4))) unsigned short ushort4v;

__device__ __forceinline__ unsigned short f2h(float f) {
    _Float16 h = (_Float16)f;                    // v_cvt_f16_f32 (RTE)
    return __builtin_bit_cast(unsigned short, h);
}
__device__ __forceinline__ float h2f(unsigned short u) {
    return (float)__builtin_bit_cast(_Float16, u);
}

// global->LDS DMA, 16B per lane. LDS dest = wave-uniform base + lane*16.
__device__ __forceinline__ void load_lds16(const unsigned short* g,
                                           unsigned short* l) {
    __builtin_amdgcn_global_load_lds(
        (const __attribute__((address_space(1))) unsigned int*)g,
        (__attribute__((address_space(3))) unsigned int*)l, 16, 0, 0);
}

// Prepack conv weights to f16, LDS-ready lane-major layout, cf=4:
// [cogrp64][kb][sh(9)][cf(4)][lane(64)][8ch]; 18432 f16 per (cogrp,kb).
// lane = q*16+n16 -> co = cogrp*64 + cf*16+n16, ch = q*8+j.
// msg: 1x4, gates: 2x6, cand: 1x6 chunks.
__global__ void prepack_k(const float* __restrict__ mw,
                          const float* __restrict__ gw,
                          const float* __restrict__ cw,
                          unsigned short* __restrict__ pw)
{
    const int MSG_I = 4*18432;        // 73728
    const int GAT_I = 12*18432;       // 221184
    const int CAN_I = 6*18432;        // 110592
    int idx = blockIdx.x*256 + threadIdx.x;
    const float* w; int cin, nkb, rel; unsigned short* base;
    if (idx < MSG_I)              { w=mw; cin=128; nkb=4; rel=idx;              base=pw; }
    else if (idx < MSG_I+GAT_I)   { w=gw; cin=192; nkb=6; rel=idx-MSG_I;        base=pw+73728; }
    else if (idx < MSG_I+GAT_I+CAN_I) { w=cw; cin=192; nkb=6; rel=idx-MSG_I-GAT_I; base=pw+294912; }
    else return;
    int chunk = rel / 18432, r = rel - chunk*18432;
    int j = r & 7, lane = (r >> 3) & 63, cfsh = r >> 9;   // cfsh 0..35
    int cf = cfsh & 3, sh = cfsh >> 2;
    int q = lane >> 4, n16 = lane & 15;
    int co_l = cf*16 + n16, ch = q*8 + j;
    int cogrp = chunk / nkb, kb = chunk - cogrp*nkb;
    float f = w[(((long)(cogrp*64 + co_l))*cin + kb*32+ch)*9 + sh];
    base[(size_t)chunk*18432 + r] = f2h(f);
}

// Convert x (2 agents x 4 t) fp32 planar -> f16 interleaved [t][half][pix][32].
__global__ void convert_all_k(const float* __restrict__ x,
                              unsigned short* __restrict__ xb0_all,
                              unsigned short* __restrict__ xb1_all)
{
    int idx = blockIdx.x*256 + threadIdx.x;      // 4,505,600 total
    int cp   = idx & 15;
    int rest = idx >> 4;
    int px4  = rest % 17600;
    int r2   = rest / 17600;                      // 0..15
    int hb = r2 & 1, ag = (r2 >> 1) & 1, t = r2 >> 2;
    const float* src = x + ((size_t)(ag*4 + t))*CHW
                         + (size_t)(hb*32 + 2*cp)*HWSZ + (size_t)px4*4;
    float4 a = *(const float4*)src;
    float4 b = *(const float4*)(src + HWSZ);
    unsigned int* dst = (unsigned int*)((ag ? xb1_all : xb0_all)
                        + (size_t)t*CHW + (size_t)hb*HWSZ*32) + (size_t)px4*64 + cp;
    dst[0]  = (unsigned)f2h(a.x) | ((unsigned)f2h(b.x) << 16);
    dst[16] = (unsigned)f2h(a.y) | ((unsigned)f2h(b.y) << 16);
    dst[32] = (unsigned)f2h(a.z) | ((unsigned)f2h(b.z) << 16);
    dst[48] = (unsigned)f2h(a.w) | ((unsigned)f2h(b.w) << 16);
}

// Block: 64 out-ch x (16 rows x 32 cols), 512 thr = 8 waves; wave w = rows
// 2w,2w+1, all 64 co (cf=0..3). LDS: 2x input [18][34][32] f16 XOR-swz
// (39168 B) + 2x weights [9][4][64][8] (36864 B) = 152064 B -> 1 block/CU.
template<int EPI>
__global__ __launch_bounds__(512, 2)
void conv_mfma_k(const unsigned short* __restrict__ seg0b,
                 const unsigned short* __restrict__ seg1b,
                 const unsigned short* __restrict__ seg2b,
                 int nkb, int nkb_stride, int grp_base,
                 const unsigned short* __restrict__ pw,
                 const float* __restrict__ bias,
                 const unsigned short* e_hb,     // f16 interl. h_{t-1} (null @t=0)
                 const unsigned short* __restrict__ e_updb, // CAND: upd f16 interl.
                 float* out_f,                   // CAND: out[t] fp32 planar
                 unsigned short* out_b,          // MSG: aggb(t<3) GATES: rhb CAND: hb
                 unsigned short* out_b2)         // MSG: aggb3    GATES: updb
{
    __shared__ unsigned short s_in0[612*32];   // [pos=row*34+col][32ch] 39168 B
    __shared__ unsigned short s_in1[612*32];
    __shared__ unsigned short s_w0[9*4*64*8];  // [sh][cf][lane][8]     36864 B
    __shared__ unsigned short s_w1[9*4*64*8];

    const int tid  = threadIdx.x;
    const int lane = tid & 63;
    const int wv   = tid >> 6;
    const int n16  = lane & 15;
    const int q    = lane >> 4;

    const int z = blockIdx.z;
    int grp, ts = 0;
    if (EPI == EPI_MSG) { ts = z; grp = 0; } else grp = z + grp_base;

    const unsigned short* s0 = seg0b + (EPI==EPI_MSG ? (size_t)ts*CHW : 0);
    const unsigned short* s1 = seg1b + (EPI==EPI_MSG ? (size_t)ts*CHW : 0);
    unsigned short* ob = out_b;
    if (EPI == EPI_MSG) ob = (ts < 3) ? out_b + (size_t)ts*CHW : out_b2;

    const int x0p = blockIdx.x * 32;
    const int y0  = blockIdx.y * 16;

    // ---- halo descriptor (kb-invariant): 400 granules, <=1 per thread.
    int hslot = 0, hoff = 0; bool hok = false;
    if (tid < 400) {
        int hp = tid >> 2, gs = tid & 3;
        int row, col;
        if (hp < 34)      { row = 0;  col = hp; }
        else if (hp < 68) { row = 17; col = hp - 34; }
        else { int k = hp - 68; row = 1 + (k >> 1); col = (k & 1) * 33; }
        int pos = row*34 + col;
        int gy = y0 + row - 1, gx = x0p + col - 1;
        hslot = (pos << 5) + (gs << 3);
        int g = (gs ^ pos ^ (pos >> 2)) & 3;
        if ((unsigned)gy < (unsigned)HH && (unsigned)gx < (unsigned)WW) {
            hok = true;
            hoff = ((gy*WW + gx) << 5) + (g << 3);
        }
    }

    auto srcof = [&](int kb) -> const unsigned short* {
        return ((kb < 2) ? s0 : (kb < 4) ? s1 : seg2b) + (size_t)(kb & 1)*HWSZ*32;
    };

    // ---- stage tile kb into (bin, bw); halo -> hreg. Interior + weights
    // via global_load_lds (LDS linear, source inverse-swizzled). Rows with
    // gy >= HH skipped (slots stay pre-zeroed); branches are wave-uniform.
    auto stage = [&](int kb, unsigned short* bin, unsigned short* bw, uint4v& hreg) {
        const unsigned short* src = srcof(kb);
#pragma unroll
        for (int j = 0; j < 4; ++j) {           // interior: chunks wv+8j
            const int c    = wv + 8*j;          // 0..31
            const int row  = 1 + (c >> 1);
            const int gy   = y0 + row - 1;
            if ((unsigned)gy < (unsigned)HH) {
                const int colh = c & 1;
                const int p0   = row*34 + 1 + colh*16;
                const int pl   = p0 + (lane >> 2);
                const int g    = ((lane & 3) ^ pl ^ (pl >> 2)) & 3;
                const int gx   = x0p + colh*16 + (lane >> 2);
                load_lds16(src + (((size_t)(gy*WW + gx)) << 5) + (g << 3),
                           &bin[(size_t)p0 << 5]);
            }
        }
        {   // weights: 36 chunks of 1024B; wave wv does chunks wv+8i
            const unsigned short* wsrc = pw + (size_t)(grp*nkb_stride + kb)*18432;
#pragma unroll
            for (int i = 0; i < 5; ++i) {
                const int ch = wv + 8*i;        // 0..39, skip >=36
                if (ch < 36)
                    load_lds16(wsrc + ch*512 + (size_t)lane*8, &bw[(size_t)ch*512]);
            }
        }
        hreg = *(const uint4v*)(src + hoff);    // halo -> reg (clamped addr)
    };

    f32x4 acc[4][4];
#pragma unroll
    for (int cf=0; cf<4; ++cf)
#pragma unroll
        for (int p=0; p<4; ++p) acc[cf][p] = (f32x4){0.f,0.f,0.f,0.f};

    auto compute = [&](const unsigned short* sin, const unsigned short* swt) {
#pragma unroll
        for (int ky = 0; ky < 3; ++ky) {
#pragma unroll
            for (int kx = 0; kx < 3; ++kx) {
                const int sh = ky*3 + kx;
                f16x8 aw[4];
#pragma unroll
                for (int cf = 0; cf < 4; ++cf)
                    aw[cf] = *(const f16x8*)&swt[((sh*4 + cf)*64 + lane)*8];
#pragma unroll
                for (int p = 0; p < 4; ++p) {
                    const int rl = 2*wv + (p >> 1) + ky;
                    const int cl = 16*(p & 1) + n16 + kx;
                    const int pos = rl*34 + cl;
                    const int sw = (q ^ pos ^ (pos >> 2)) & 3;
                    f16x8 bfr = *(const f16x8*)&sin[(pos << 5) + (sw << 3)];
#pragma unroll
                    for (int cf = 0; cf < 4; ++cf)
                        acc[cf][p] = __builtin_amdgcn_mfma_f32_16x16x32_f16(
                                         aw[cf], bfr, acc[cf][p], 0, 0, 0);
                }
            }
        }
    };

    // ---- pre-zero both input buffers (halo-OOB / skipped-row slots must
    // read as 0; loads overwrite the live slots each kb).
    {
        const uint4v z4 = (uint4v){0u,0u,0u,0u};
        for (int i = tid; i < 2448; i += 512) {
            *(uint4v*)&s_in0[(size_t)i*8] = z4;
            *(uint4v*)&s_in1[(size_t)i*8] = z4;
        }
    }
    __syncthreads();             // zeros visible before any DMA lands

    uint4v h0, h1;
    stage(0, s_in0, s_w0, h0);   // prologue

    for (int kb = 0; kb < nkb; kb += 2) {   // nkb is even (4 or 6)
        // ===== phase A: ready buf0 (kb), prefetch kb+1 -> buf1
        if (hok) *(uint4v*)&s_in0[hslot] = h0;    // waits h0 (vmcnt dep)
        __syncthreads();         // implicit vmcnt(0): kb's DMAs landed
        stage(kb + 1, s_in1, s_w1, h1);
        __builtin_amdgcn_sched_barrier(0);        // pin DMA issue before reads
        compute(s_in0, s_w0);
        // ===== phase B: ready buf1 (kb+1), prefetch kb+2 -> buf0
        if (hok) *(uint4v*)&s_in1[hslot] = h1;
        __syncthreads();
        if (kb + 2 < nkb) {
            stage(kb + 2, s_in0, s_w0, h0);
            __builtin_amdgcn_sched_barrier(0);
        }
        compute(s_in1, s_w1);
    }

    // ---- epilogue. C/D: pixel = lane&15, co = (lane>>4)*4 + reg
#pragma unroll
    for (int cf = 0; cf < 4; ++cf) {
        const int half   = cf >> 1;                // 32-ch half within co64
        const int cobase = grp*64 + cf*16 + q*4;   // global co of reg 0
        const int cmod   = (cf & 1)*16 + q*4;      // co within 32-plane
#pragma unroll
        for (int p = 0; p < 4; ++p) {
            const int row = y0 + 2*wv + (p >> 1);
            const int col = x0p + 16*(p & 1) + n16;
            if (row >= HH) continue;
            const long pix = (long)row*WW + col;
            const size_t iidx = (((size_t)half*HWSZ + pix) << 5) + cmod;
            float v[4];
#pragma unroll
            for (int r = 0; r < 4; ++r) v[r] = acc[cf][p][r] + bias[cobase + r];

            if (EPI == EPI_MSG) {
                ushort4v xv = *(const ushort4v*)&s0[iidx];
                ushort4v s;
#pragma unroll
                for (int r = 0; r < 4; ++r)
                    s[r] = f2h(0.5f*(h2f(xv[r]) + v[r]));
                *(ushort4v*)&ob[iidx] = s;
            } else if (EPI == EPI_GATES) {
                if (grp == 0) {  // reset block -> rh = sigmoid * h
                    ushort4v hv = e_hb ? *(const ushort4v*)&e_hb[iidx]
                                       : (ushort4v){0,0,0,0};
                    ushort4v s;
#pragma unroll
                    for (int r = 0; r < 4; ++r) {
                        float g = 1.f/(1.f + __expf(-v[r]));
                        s[r] = f2h(g * h2f(hv[r]));
                    }
                    *(ushort4v*)&out_b[iidx] = s;
                } else {         // update block -> updb
                    ushort4v s;
#pragma unroll
                    for (int r = 0; r < 4; ++r)
                        s[r] = f2h(1.f/(1.f + __expf(-v[r])));
                    *(ushort4v*)&out_b2[iidx] = s;
                }
            } else {             // CAND: h_next -> out fp32 planar + hb f16
                ushort4v uv = *(const ushort4v*)&e_updb[iidx];
                ushort4v hv = e_hb ? *(const ushort4v*)&e_hb[iidx]
                                   : (ushort4v){0,0,0,0};
                ushort4v s;
#pragma unroll
                for (int r = 0; r < 4; ++r) {
                    float cnm = tanhf(v[r]);
                    float u   = h2f(uv[r]);
                    float hn  = (1.f - u)*h2f(hv[r]) + u*cnm;
                    out_f[(long)(cobase+r)*HWSZ + pix] = hn;
                    s[r] = f2h(hn);
                }
                *(ushort4v*)&out_b[iidx] = s;
            }
        }
    }
}

// ws (u16 units): xb0_all 4C | aggb3 C | rhb C | updb C | hb C | pw 405504
//   = 72.9 MB.   d_out aliases: xb1_all = out[0..1] (dead until step 0),
//   aggb[0..2] = out[2..3] (aggb[t] dead before its region is written).
extern "C" void kernel_launch(void* const* d_in, const int* in_sizes, int n_in,
                              void* d_out, int out_size, void* d_ws, size_t ws_size,
                              hipStream_t stream)
{
    const float* x       = (const float*)d_in[0];
    const float* msg_w   = (const float*)d_in[1];
    const float* msg_b   = (const float*)d_in[2];
    const float* gates_w = (const float*)d_in[3];
    const float* gates_b = (const float*)d_in[4];
    const float* can_w   = (const float*)d_in[5];
    const float* can_b   = (const float*)d_in[6];
    float* out = (float*)d_out;

    unsigned short* W       = (unsigned short*)d_ws;
    unsigned short* xb0_all = W;                  // [4][2][HWSZ][32]
    unsigned short* aggb3   = W + 4*CHW;
    unsigned short* rhb     = W + 5*CHW;
    unsigned short* updb    = W + 6*CHW;
    unsigned short* hb      = W + 7*CHW;
    unsigned short* pw      = W + 8*CHW;          // 405504 u16
    unsigned short* pw_msg  = pw;
    unsigned short* pw_gat  = pw + 73728;
    unsigned short* pw_can  = pw + 294912;

    unsigned short* outU16   = (unsigned short*)d_out;
    unsigned short* xb1_all  = outU16;            // 4*CHW u16 = out[0..1]
    unsigned short* aggbase  = outU16 + 4*CHW;    // aggb[0..2] = out[2..3]

    prepack_k<<<dim3(1584), dim3(256), 0, stream>>>(msg_w, gates_w, can_w, pw);
    convert_all_k<<<dim3(17600), dim3(256), 0, stream>>>(x, xb0_all, xb1_all);

    // msg for all 4 t in one dispatch: Cin=[x0|x1], Cout=64 -> aggb[t]
    conv_mfma_k<EPI_MSG><<<dim3(11,13,4), dim3(512), 0, stream>>>(
        xb0_all, xb1_all, nullptr, 4, 4, 0, pw_msg, msg_b,
        nullptr, nullptr, nullptr, aggbase, aggb3);

    for (int t = 0; t < 4; ++t) {
        const unsigned short* xt  = xb0_all + (size_t)t*CHW;
        const unsigned short* agt = (t < 3) ? aggbase + (size_t)t*CHW : aggb3;
        const unsigned short* hprev = t ? hb : nullptr;

        // gates: Cin=[x|agg|h], Cout=128; block z=0 -> reset (co 0..63),
        // z=1 -> update (co 64..127). t=0: h==0 -> reset*h==0 and
        // CAND(nkb=4) never reads rhb, so launch update half only.
        conv_mfma_k<EPI_GATES><<<dim3(11,13, t ? 2 : 1), dim3(512), 0, stream>>>(
            xt, agt, hb, t ? 6 : 4, 6, t ? 0 : 1, pw_gat, gates_b,
            hprev, nullptr, nullptr, rhb, updb);
        // cand: Cin=[x|agg|rh], Cout=64 -> out[t] fp32 + hb f16
        conv_mfma_k<EPI_CAND><<<dim3(11,13,1), dim3(512), 0, stream>>>(
            xt, agt, rhb, t ? 6 : 4, 6, 0, pw_can, can_b,
            hprev, updb, out + (size_t)t*CHW, hb, nullptr);
    }
}